// Round 13
// baseline (198.184 us; speedup 1.0000x reference)
//
#include <hip/hip_runtime.h>

// Problem constants (B=1)
#define NQ   512
#define NKV  2562
#define CH   64
#define QB   4           // queries per attn block
#define BT   256         // attn block threads (4 waves)
#define NJQ  8           // j-range split
#define JQ   321         // ceil(NKV/8)
#define PSTRIDE 260      // per (qquad, eighth): s[4], o[64] x4
#define LOG2E 1.44269504088896340736f

// gemm grid partition
#define KVROWS 8
#define NKVB ((NKV + KVROWS - 1) / KVROWS)   // 321
#define QROWS 16
#define NQB (NQ / QROWS)                     // 32
#define NCB  41                              // ceil(NKV*4/256) for kvc4 prescale

// raw 1-instruction exp2 (OCML exp2f adds range-fixup code; v_exp_f32 IS 2^x)
static __device__ __forceinline__ float exp2_raw(float x) {
  float r; asm("v_exp_f32 %0, %1" : "=v"(r) : "v"(x)); return r;
}
// 2^(-|x|): neg+abs are free VOP3 input modifiers
static __device__ __forceinline__ float exp2_negabs(float x) {
  float r; asm("v_exp_f32 %0, -abs(%1)" : "=v"(r) : "v"(x)); return r;
}
// inputs prescaled by log2e: exp(-|q-k|) == 2^(-|q'-k'|)
#define E2(a, b) exp2_negabs((a) - (b))
// 4-channel partial score for one query-float4 against one k-float4
#define T4(qf, kf) ((E2((qf).x, (kf).x) + E2((qf).y, (kf).y)) + \
                    (E2((qf).z, (kf).z) + E2((qf).w, (kf).w)))

// ---------------------------------------------------------------------------
// Kernel A: q_ = (q @ Wq)*log2e ; kv_ = kv @ Wkv with k-half *log2e ;
//           kvc4[j] = {kvc[j]*log2e, 0} packed float4 ; zero merge counters.
// ---------------------------------------------------------------------------
__global__ __launch_bounds__(256) void gemm_qkv(
    const float* __restrict__ q, const float* __restrict__ kv,
    const float* __restrict__ Wq, const float* __restrict__ Wkv,
    const float* __restrict__ kvc, float* __restrict__ qp,
    float* __restrict__ kvp, float* __restrict__ kvc4,
    int* __restrict__ counters) {
  const int tid = threadIdx.x;
  if (blockIdx.x < NKVB) {
    const int j0 = blockIdx.x * KVROWS;
    __shared__ float s_in[KVROWS][CH];
    if (tid < KVROWS * (CH / 4)) {
      int r = tid >> 4, g = tid & 15;
      int j = j0 + r;
      float4 v = (j < NKV) ? ((const float4*)(kv + (size_t)j * CH))[g]
                           : make_float4(0.f, 0.f, 0.f, 0.f);
      ((float4*)&s_in[r][0])[g] = v;
    }
    __syncthreads();
    const int r = tid >> 5;
    const int mg = (tid & 31) * 4;
    float4 acc = make_float4(0.f, 0.f, 0.f, 0.f);
#pragma unroll 16
    for (int rr = 0; rr < CH; ++rr) {
      float a = s_in[r][rr];
      float4 w = *(const float4*)(Wkv + (size_t)rr * 2 * CH + mg);
      acc.x = fmaf(a, w.x, acc.x); acc.y = fmaf(a, w.y, acc.y);
      acc.z = fmaf(a, w.z, acc.z); acc.w = fmaf(a, w.w, acc.w);
    }
    if (mg < CH) {  // k-half: prescale by log2e
      acc.x *= LOG2E; acc.y *= LOG2E; acc.z *= LOG2E; acc.w *= LOG2E;
    }
    int j = j0 + r;
    if (j < NKV) *(float4*)(kvp + (size_t)j * 2 * CH + mg) = acc;
  } else if (blockIdx.x < NKVB + NQB) {
    const int i0 = (blockIdx.x - NKVB) * QROWS;
    __shared__ float s_in[QROWS][CH];
    {
      int r = tid >> 4, g = tid & 15;
      float4 v = ((const float4*)(q + (size_t)(i0 + r) * CH))[g];
      ((float4*)&s_in[r][0])[g] = v;
    }
    __syncthreads();
    const int r = tid >> 4;
    const int cg = (tid & 15) * 4;
    float4 acc = make_float4(0.f, 0.f, 0.f, 0.f);
#pragma unroll 16
    for (int rr = 0; rr < CH; ++rr) {
      float a = s_in[r][rr];
      float4 w = *(const float4*)(Wq + (size_t)rr * CH + cg);
      acc.x = fmaf(a, w.x, acc.x); acc.y = fmaf(a, w.y, acc.y);
      acc.z = fmaf(a, w.z, acc.z); acc.w = fmaf(a, w.w, acc.w);
    }
    acc.x *= LOG2E; acc.y *= LOG2E; acc.z *= LOG2E; acc.w *= LOG2E;
    *(float4*)(qp + (size_t)(i0 + r) * CH + cg) = acc;
  } else {
    // kvc4: prescaled, float4-padded coords; block 0 of this range also
    // zeroes the per-qquad merge counters (poisoned 0xAA by harness).
    int b = blockIdx.x - NKVB - NQB;
    if (b == 0 && tid < NQ / QB) counters[tid] = 0;
    int t = b * 256 + tid;
    if (t < NKV * 4) {
      int j = t >> 2, d = t & 3;
      kvc4[t] = (d < 3) ? kvc[(size_t)j * 3 + d] * LOG2E : 0.f;
    }
  }
}

// ---------------------------------------------------------------------------
// Kernel B: partial attention over a j-eighth for 4 queries, with fused
// merge+projection done by the LAST finishing block of each qquad
// (device-scope atomic counter; writers fence before, merger fences after).
// Block = (qquad, eighth); 256 threads (4 waves); grid 1024.
// Single-pass softmax (scores bounded ~[-2,2]; no max subtraction).
// ---------------------------------------------------------------------------
__global__ __launch_bounds__(BT, 4) void attn_part(
    const float* __restrict__ qp, const float* __restrict__ kvp,
    const float* __restrict__ qc, const float* __restrict__ kvc4,
    const float* __restrict__ Wdelta, float* __restrict__ part,
    int* __restrict__ counters, const float* __restrict__ Wproj,
    const float* __restrict__ bproj, float* __restrict__ out) {
  __shared__ float s_score[QB][JQ];    // 5136 B
  __shared__ float s_red[QB][BT];      // 4096 B
  __shared__ float s_wd[3];
  __shared__ int s_last;

  const int qquad = blockIdx.x >> 3;
  const int h = blockIdx.x & 7;
  const int i0 = qquad * QB;
  const int jlo = h * JQ;
  const int jhi = (jlo + JQ < NKV) ? jlo + JQ : NKV;

  const int tid = threadIdx.x;
  const int sub = tid & 3;
  const int c0 = sub * 16;
  const int wid = tid >> 6;
  const int lane = tid & 63;

  if (tid < 3) {
    float s = 0.f;
    for (int c = 0; c < CH; ++c) s += Wdelta[tid * CH + c];
    s_wd[tid] = s;
  }

  // 4 query slices into named registers (already *log2e); pinned
  const float4* pw = (const float4*)(qp + (size_t)(i0 + 0) * CH + c0);
  const float4* px = (const float4*)(qp + (size_t)(i0 + 1) * CH + c0);
  const float4* py = (const float4*)(qp + (size_t)(i0 + 2) * CH + c0);
  const float4* pz = (const float4*)(qp + (size_t)(i0 + 3) * CH + c0);
  float4 qw0 = pw[0], qw1 = pw[1], qw2 = pw[2], qw3 = pw[3];
  float4 qx0 = px[0], qx1 = px[1], qx2 = px[2], qx3 = px[3];
  float4 qy0 = py[0], qy1 = py[1], qy2 = py[2], qy3 = py[3];
  float4 qz0 = pz[0], qz1 = pz[1], qz2 = pz[2], qz3 = pz[3];
  asm volatile("" : "+v"(qw0.x), "+v"(qw0.y), "+v"(qw0.z), "+v"(qw0.w),
                    "+v"(qw1.x), "+v"(qw1.y), "+v"(qw1.z), "+v"(qw1.w),
                    "+v"(qw2.x), "+v"(qw2.y), "+v"(qw2.z), "+v"(qw2.w),
                    "+v"(qw3.x), "+v"(qw3.y), "+v"(qw3.z), "+v"(qw3.w));
  asm volatile("" : "+v"(qx0.x), "+v"(qx0.y), "+v"(qx0.z), "+v"(qx0.w),
                    "+v"(qx1.x), "+v"(qx1.y), "+v"(qx1.z), "+v"(qx1.w),
                    "+v"(qx2.x), "+v"(qx2.y), "+v"(qx2.z), "+v"(qx2.w),
                    "+v"(qx3.x), "+v"(qx3.y), "+v"(qx3.z), "+v"(qx3.w));
  asm volatile("" : "+v"(qy0.x), "+v"(qy0.y), "+v"(qy0.z), "+v"(qy0.w),
                    "+v"(qy1.x), "+v"(qy1.y), "+v"(qy1.z), "+v"(qy1.w),
                    "+v"(qy2.x), "+v"(qy2.y), "+v"(qy2.z), "+v"(qy2.w),
                    "+v"(qy3.x), "+v"(qy3.y), "+v"(qy3.z), "+v"(qy3.w));
  asm volatile("" : "+v"(qz0.x), "+v"(qz0.y), "+v"(qz0.z), "+v"(qz0.w),
                    "+v"(qz1.x), "+v"(qz1.y), "+v"(qz1.z), "+v"(qz1.w),
                    "+v"(qz2.x), "+v"(qz2.y), "+v"(qz2.z), "+v"(qz2.w),
                    "+v"(qz3.x), "+v"(qz3.y), "+v"(qz3.z), "+v"(qz3.w));

  // query coords (prescaled), named scalars
  float cw0 = qc[(size_t)(i0 + 0) * 3 + 0] * LOG2E;
  float cw1 = qc[(size_t)(i0 + 0) * 3 + 1] * LOG2E;
  float cw2 = qc[(size_t)(i0 + 0) * 3 + 2] * LOG2E;
  float cx0 = qc[(size_t)(i0 + 1) * 3 + 0] * LOG2E;
  float cx1 = qc[(size_t)(i0 + 1) * 3 + 1] * LOG2E;
  float cx2 = qc[(size_t)(i0 + 1) * 3 + 2] * LOG2E;
  float cy0 = qc[(size_t)(i0 + 2) * 3 + 0] * LOG2E;
  float cy1 = qc[(size_t)(i0 + 2) * 3 + 1] * LOG2E;
  float cy2 = qc[(size_t)(i0 + 2) * 3 + 2] * LOG2E;
  float cz0 = qc[(size_t)(i0 + 3) * 3 + 0] * LOG2E;
  float cz1 = qc[(size_t)(i0 + 3) * 3 + 1] * LOG2E;
  float cz2 = qc[(size_t)(i0 + 3) * 3 + 2] * LOG2E;
  __syncthreads();
  const float wd0 = s_wd[0], wd1 = s_wd[1], wd2 = s_wd[2];
  const float pscale = (1.0f / 64.0f) * LOG2E;   // p = 2^(s * pscale)

  // ---- phase 1: p = exp(score) for 4 queries, fused running sums ----
  float lsw = 0.f, lsx = 0.f, lsy = 0.f, lsz = 0.f;
  for (int j = jlo + (tid >> 2); j < jhi; j += BT / 4) {
    const float4* kr = (const float4*)(kvp + (size_t)j * 128 + c0);
    float4 k0 = kr[0], k1 = kr[1], k2 = kr[2], k3 = kr[3];
    float4 cc = *(const float4*)(kvc4 + (size_t)j * 4);

    float sw = (T4(qw0, k0) + T4(qw1, k1)) + (T4(qw2, k2) + T4(qw3, k3));
    float sx = (T4(qx0, k0) + T4(qx1, k1)) + (T4(qx2, k2) + T4(qx3, k3));
    float sy = (T4(qy0, k0) + T4(qy1, k1)) + (T4(qy2, k2) + T4(qy3, k3));
    float sz = (T4(qz0, k0) + T4(qz1, k1)) + (T4(qz2, k2) + T4(qz3, k3));
    sw += __shfl_xor(sw, 1); sw += __shfl_xor(sw, 2);
    sx += __shfl_xor(sx, 1); sx += __shfl_xor(sx, 2);
    sy += __shfl_xor(sy, 1); sy += __shfl_xor(sy, 2);
    sz += __shfl_xor(sz, 1); sz += __shfl_xor(sz, 2);
    if (sub == 0) {
      int jj = j - jlo;
      sw += E2(cw0, cc.x) * wd0 + E2(cw1, cc.y) * wd1 + E2(cw2, cc.z) * wd2;
      sx += E2(cx0, cc.x) * wd0 + E2(cx1, cc.y) * wd1 + E2(cx2, cc.z) * wd2;
      sy += E2(cy0, cc.x) * wd0 + E2(cy1, cc.y) * wd1 + E2(cy2, cc.z) * wd2;
      sz += E2(cz0, cc.x) * wd0 + E2(cz1, cc.y) * wd1 + E2(cz2, cc.z) * wd2;
      float p0 = exp2_raw(sw * pscale);
      float p1 = exp2_raw(sx * pscale);
      float p2 = exp2_raw(sy * pscale);
      float p3 = exp2_raw(sz * pscale);
      s_score[0][jj] = p0; s_score[1][jj] = p1;
      s_score[2][jj] = p2; s_score[3][jj] = p3;
      lsw += p0; lsx += p1; lsy += p2; lsz += p3;
    }
  }

  // ---- sums: wave shfl reduce + cross-wave combine ----
#pragma unroll
  for (int off = 1; off < 64; off <<= 1) {
    lsw += __shfl_xor(lsw, off);
    lsx += __shfl_xor(lsx, off);
    lsy += __shfl_xor(lsy, off);
    lsz += __shfl_xor(lsz, off);
  }
  if (lane == 0) {
    s_red[0][wid] = lsw; s_red[1][wid] = lsx;
    s_red[2][wid] = lsy; s_red[3][wid] = lsz;
  }
  __syncthreads();
  float tw = s_red[0][0], tx = s_red[1][0], ty = s_red[2][0], tz = s_red[3][0];
#pragma unroll
  for (int w = 1; w < BT / 64; ++w) {
    tw += s_red[0][w]; tx += s_red[1][w];
    ty += s_red[2][w]; tz += s_red[3][w];
  }
  __syncthreads();   // done reading s_red before reuse; s_score visible

  // ---- phase 2: unnormalized o[c] = sum_j p_j * v[j,c], 4 j-groups ----
  const int c = tid & 63, g = tid >> 6;   // g in [0,4)
  float aw = 0.f, ax = 0.f, ay = 0.f, az = 0.f;
#pragma unroll 8
  for (int j2 = jlo + g; j2 < jhi; j2 += 4) {
    float v = kvp[(size_t)j2 * 128 + 64 + c];
    int jj = j2 - jlo;
    aw = fmaf(s_score[0][jj], v, aw);
    ax = fmaf(s_score[1][jj], v, ax);
    ay = fmaf(s_score[2][jj], v, ay);
    az = fmaf(s_score[3][jj], v, az);
  }
  s_red[0][tid] = aw; s_red[1][tid] = ax;
  s_red[2][tid] = ay; s_red[3][tid] = az;
  __syncthreads();

  float* P = part + (size_t)(qquad * NJQ + h) * PSTRIDE;
  if (g == 0) {
    float uw = 0.f, ux = 0.f, uy = 0.f, uz = 0.f;
#pragma unroll
    for (int gg = 0; gg < 4; ++gg) {
      uw += s_red[0][gg * 64 + c];
      ux += s_red[1][gg * 64 + c];
      uy += s_red[2][gg * 64 + c];
      uz += s_red[3][gg * 64 + c];
    }
    P[4 + 0 * 64 + c] = uw;
    P[4 + 1 * 64 + c] = ux;
    P[4 + 2 * 64 + c] = uy;
    P[4 + 3 * 64 + c] = uz;
    if (c == 0) { P[0] = tw; P[1] = tx; P[2] = ty; P[3] = tz; }
  }

  // ---- fused merge: last finishing block of this qquad does merge+proj ----
  __threadfence();                 // make partials visible device-wide
  if (tid == 0) {
    int old = atomicAdd(&counters[qquad], 1);
    s_last = (old == NJQ - 1) ? 1 : 0;
  }
  __syncthreads();
  if (!s_last) return;
  __threadfence();                 // acquire: see other blocks' partials

  const int qs = tid >> 6;         // query within quad; c = tid & 63
  float ssum = 0.f, osum = 0.f;
#pragma unroll
  for (int hh = 0; hh < NJQ; ++hh) {
    const float* Pm = part + (size_t)(qquad * NJQ + hh) * PSTRIDE;
    ssum += Pm[qs];
    osum += Pm[4 + qs * 64 + c];
  }
  s_red[0][tid] = osum / ssum;     // s_red[0][qs*64 + c]
  __syncthreads();
  float acc = 0.f;
#pragma unroll 16
  for (int r = 0; r < CH; ++r)
    acc = fmaf(s_red[0][(tid & ~63) + r], Wproj[r * CH + c], acc);
  out[(size_t)(i0 + qs) * CH + c] = acc + bproj[c];
}

// ---------------------------------------------------------------------------
extern "C" void kernel_launch(void* const* d_in, const int* in_sizes, int n_in,
                              void* d_out, int out_size, void* d_ws, size_t ws_size,
                              hipStream_t stream) {
  const float* q      = (const float*)d_in[0];
  const float* qc     = (const float*)d_in[1];
  const float* kv     = (const float*)d_in[2];
  const float* kvc    = (const float*)d_in[3];
  const float* Wq     = (const float*)d_in[4];
  const float* Wkv    = (const float*)d_in[5];
  const float* Wdelta = (const float*)d_in[6];
  const float* Wproj  = (const float*)d_in[7];
  const float* bproj  = (const float*)d_in[8];
  float* outp = (float*)d_out;

  float* qp   = (float*)d_ws;                              // 512*64
  float* kvp  = qp + NQ * CH;                              // 2562*128
  float* part = kvp + (size_t)NKV * 2 * CH;                // 128*8*260
  float* kvc4 = part + (size_t)(NQ / QB) * NJQ * PSTRIDE;  // 2562*4
  int* counters = (int*)(kvc4 + (size_t)NKV * 4);          // 128 ints

  gemm_qkv<<<NKVB + NQB + NCB, 256, 0, stream>>>(q, kv, Wq, Wkv, kvc, qp, kvp,
                                                 kvc4, counters);
  attn_part<<<(NQ / QB) * NJQ, BT, 0, stream>>>(qp, kvp, qc, kvc4, Wdelta, part,
                                                counters, Wproj, bproj, outp);
}

// Round 14
// 102.689 us; speedup vs baseline: 1.9299x; 1.9299x over previous
//
#include <hip/hip_runtime.h>

// Problem constants (B=1)
#define NQ   512
#define NKV  2562
#define CH   64
#define QB   4           // queries per attn block
#define BT   256         // attn block threads (4 waves)
#define NJQ  8           // j-range split
#define JQ   321         // ceil(NKV/8)
#define PSTRIDE 260      // per (qquad, eighth): s[4], o0[64..] x4
#define LOG2E 1.44269504088896340736f

// gemm grid partition
#define KVROWS 8
#define NKVB ((NKV + KVROWS - 1) / KVROWS)   // 321
#define QROWS 16
#define NQB (NQ / QROWS)                     // 32
#define NCB  41                              // ceil(NKV*4/256) for kvc4 prescale

// raw 1-instruction exp2 (OCML exp2f adds range-fixup code; v_exp_f32 IS 2^x)
static __device__ __forceinline__ float exp2_raw(float x) {
  float r; asm("v_exp_f32 %0, %1" : "=v"(r) : "v"(x)); return r;
}
// 2^(-|x|): neg+abs are free VOP3 input modifiers
static __device__ __forceinline__ float exp2_negabs(float x) {
  float r; asm("v_exp_f32 %0, -abs(%1)" : "=v"(r) : "v"(x)); return r;
}
// inputs prescaled by log2e: exp(-|q-k|) == 2^(-|q'-k'|)
#define E2(a, b) exp2_negabs((a) - (b))
// 4-channel partial score for one query-float4 against one k-float4
#define T4(qf, kf) ((E2((qf).x, (kf).x) + E2((qf).y, (kf).y)) + \
                    (E2((qf).z, (kf).z) + E2((qf).w, (kf).w)))

// ---------------------------------------------------------------------------
// Kernel A: q_ = (q @ Wq)*log2e ; kv_ = kv @ Wkv with k-half *log2e ;
//           kvc4[j] = {kvc[j]*log2e, 0} packed float4.
// ---------------------------------------------------------------------------
__global__ __launch_bounds__(256) void gemm_qkv(
    const float* __restrict__ q, const float* __restrict__ kv,
    const float* __restrict__ Wq, const float* __restrict__ Wkv,
    const float* __restrict__ kvc, float* __restrict__ qp,
    float* __restrict__ kvp, float* __restrict__ kvc4) {
  const int tid = threadIdx.x;
  if (blockIdx.x < NKVB) {
    const int j0 = blockIdx.x * KVROWS;
    __shared__ float s_in[KVROWS][CH];
    if (tid < KVROWS * (CH / 4)) {
      int r = tid >> 4, g = tid & 15;
      int j = j0 + r;
      float4 v = (j < NKV) ? ((const float4*)(kv + (size_t)j * CH))[g]
                           : make_float4(0.f, 0.f, 0.f, 0.f);
      ((float4*)&s_in[r][0])[g] = v;
    }
    __syncthreads();
    const int r = tid >> 5;
    const int mg = (tid & 31) * 4;
    float4 acc = make_float4(0.f, 0.f, 0.f, 0.f);
#pragma unroll 16
    for (int rr = 0; rr < CH; ++rr) {
      float a = s_in[r][rr];
      float4 w = *(const float4*)(Wkv + (size_t)rr * 2 * CH + mg);
      acc.x = fmaf(a, w.x, acc.x); acc.y = fmaf(a, w.y, acc.y);
      acc.z = fmaf(a, w.z, acc.z); acc.w = fmaf(a, w.w, acc.w);
    }
    if (mg < CH) {  // k-half: prescale by log2e
      acc.x *= LOG2E; acc.y *= LOG2E; acc.z *= LOG2E; acc.w *= LOG2E;
    }
    int j = j0 + r;
    if (j < NKV) *(float4*)(kvp + (size_t)j * 2 * CH + mg) = acc;
  } else if (blockIdx.x < NKVB + NQB) {
    const int i0 = (blockIdx.x - NKVB) * QROWS;
    __shared__ float s_in[QROWS][CH];
    {
      int r = tid >> 4, g = tid & 15;
      float4 v = ((const float4*)(q + (size_t)(i0 + r) * CH))[g];
      ((float4*)&s_in[r][0])[g] = v;
    }
    __syncthreads();
    const int r = tid >> 4;
    const int cg = (tid & 15) * 4;
    float4 acc = make_float4(0.f, 0.f, 0.f, 0.f);
#pragma unroll 16
    for (int rr = 0; rr < CH; ++rr) {
      float a = s_in[r][rr];
      float4 w = *(const float4*)(Wq + (size_t)rr * CH + cg);
      acc.x = fmaf(a, w.x, acc.x); acc.y = fmaf(a, w.y, acc.y);
      acc.z = fmaf(a, w.z, acc.z); acc.w = fmaf(a, w.w, acc.w);
    }
    acc.x *= LOG2E; acc.y *= LOG2E; acc.z *= LOG2E; acc.w *= LOG2E;
    *(float4*)(qp + (size_t)(i0 + r) * CH + cg) = acc;
  } else {
    // kvc4: prescaled, float4-padded coords
    int t = (blockIdx.x - NKVB - NQB) * 256 + tid;
    if (t < NKV * 4) {
      int j = t >> 2, d = t & 3;
      kvc4[t] = (d < 3) ? kvc[(size_t)j * 3 + d] * LOG2E : 0.f;
    }
  }
}

// ---------------------------------------------------------------------------
// Kernel B1: partial attention over a j-eighth for 4 queries.
// Block = (qquad, eighth); 256 threads (4 waves); grid 1024 = 4 blocks/CU.
// Channel-split 4-way (lane sub = tid&3 owns channels [16*sub, +16)).
// Single-pass (no max subtraction — scores bounded ~[-2,2]).
// ---------------------------------------------------------------------------
__global__ __launch_bounds__(BT, 4) void attn_part(
    const float* __restrict__ qp, const float* __restrict__ kvp,
    const float* __restrict__ qc, const float* __restrict__ kvc4,
    const float* __restrict__ Wdelta, float* __restrict__ part) {
  __shared__ float s_score[QB][JQ];    // 5136 B
  __shared__ float s_red[QB][BT];      // 4096 B
  __shared__ float s_wd[3];

  const int qquad = blockIdx.x >> 3;
  const int h = blockIdx.x & 7;
  const int i0 = qquad * QB;
  const int jlo = h * JQ;
  const int jhi = (jlo + JQ < NKV) ? jlo + JQ : NKV;

  const int tid = threadIdx.x;
  const int sub = tid & 3;
  const int c0 = sub * 16;
  const int wid = tid >> 6;
  const int lane = tid & 63;

  if (tid < 3) {
    float s = 0.f;
    for (int c = 0; c < CH; ++c) s += Wdelta[tid * CH + c];
    s_wd[tid] = s;
  }

  // 4 query slices into named registers (already *log2e); pinned
  const float4* pw = (const float4*)(qp + (size_t)(i0 + 0) * CH + c0);
  const float4* px = (const float4*)(qp + (size_t)(i0 + 1) * CH + c0);
  const float4* py = (const float4*)(qp + (size_t)(i0 + 2) * CH + c0);
  const float4* pz = (const float4*)(qp + (size_t)(i0 + 3) * CH + c0);
  float4 qw0 = pw[0], qw1 = pw[1], qw2 = pw[2], qw3 = pw[3];
  float4 qx0 = px[0], qx1 = px[1], qx2 = px[2], qx3 = px[3];
  float4 qy0 = py[0], qy1 = py[1], qy2 = py[2], qy3 = py[3];
  float4 qz0 = pz[0], qz1 = pz[1], qz2 = pz[2], qz3 = pz[3];
  asm volatile("" : "+v"(qw0.x), "+v"(qw0.y), "+v"(qw0.z), "+v"(qw0.w),
                    "+v"(qw1.x), "+v"(qw1.y), "+v"(qw1.z), "+v"(qw1.w),
                    "+v"(qw2.x), "+v"(qw2.y), "+v"(qw2.z), "+v"(qw2.w),
                    "+v"(qw3.x), "+v"(qw3.y), "+v"(qw3.z), "+v"(qw3.w));
  asm volatile("" : "+v"(qx0.x), "+v"(qx0.y), "+v"(qx0.z), "+v"(qx0.w),
                    "+v"(qx1.x), "+v"(qx1.y), "+v"(qx1.z), "+v"(qx1.w),
                    "+v"(qx2.x), "+v"(qx2.y), "+v"(qx2.z), "+v"(qx2.w),
                    "+v"(qx3.x), "+v"(qx3.y), "+v"(qx3.z), "+v"(qx3.w));
  asm volatile("" : "+v"(qy0.x), "+v"(qy0.y), "+v"(qy0.z), "+v"(qy0.w),
                    "+v"(qy1.x), "+v"(qy1.y), "+v"(qy1.z), "+v"(qy1.w),
                    "+v"(qy2.x), "+v"(qy2.y), "+v"(qy2.z), "+v"(qy2.w),
                    "+v"(qy3.x), "+v"(qy3.y), "+v"(qy3.z), "+v"(qy3.w));
  asm volatile("" : "+v"(qz0.x), "+v"(qz0.y), "+v"(qz0.z), "+v"(qz0.w),
                    "+v"(qz1.x), "+v"(qz1.y), "+v"(qz1.z), "+v"(qz1.w),
                    "+v"(qz2.x), "+v"(qz2.y), "+v"(qz2.z), "+v"(qz2.w),
                    "+v"(qz3.x), "+v"(qz3.y), "+v"(qz3.z), "+v"(qz3.w));

  // query coords (prescaled), named scalars
  float cw0 = qc[(size_t)(i0 + 0) * 3 + 0] * LOG2E;
  float cw1 = qc[(size_t)(i0 + 0) * 3 + 1] * LOG2E;
  float cw2 = qc[(size_t)(i0 + 0) * 3 + 2] * LOG2E;
  float cx0 = qc[(size_t)(i0 + 1) * 3 + 0] * LOG2E;
  float cx1 = qc[(size_t)(i0 + 1) * 3 + 1] * LOG2E;
  float cx2 = qc[(size_t)(i0 + 1) * 3 + 2] * LOG2E;
  float cy0 = qc[(size_t)(i0 + 2) * 3 + 0] * LOG2E;
  float cy1 = qc[(size_t)(i0 + 2) * 3 + 1] * LOG2E;
  float cy2 = qc[(size_t)(i0 + 2) * 3 + 2] * LOG2E;
  float cz0 = qc[(size_t)(i0 + 3) * 3 + 0] * LOG2E;
  float cz1 = qc[(size_t)(i0 + 3) * 3 + 1] * LOG2E;
  float cz2 = qc[(size_t)(i0 + 3) * 3 + 2] * LOG2E;
  __syncthreads();
  const float wd0 = s_wd[0], wd1 = s_wd[1], wd2 = s_wd[2];
  const float pscale = (1.0f / 64.0f) * LOG2E;   // p = 2^(s * pscale)

  // ---- phase 1: p = exp(score) for 4 queries, fused running sums ----
  float lsw = 0.f, lsx = 0.f, lsy = 0.f, lsz = 0.f;
  for (int j = jlo + (tid >> 2); j < jhi; j += BT / 4) {
    const float4* kr = (const float4*)(kvp + (size_t)j * 128 + c0);
    float4 k0 = kr[0], k1 = kr[1], k2 = kr[2], k3 = kr[3];
    float4 cc = *(const float4*)(kvc4 + (size_t)j * 4);

    float sw = (T4(qw0, k0) + T4(qw1, k1)) + (T4(qw2, k2) + T4(qw3, k3));
    float sx = (T4(qx0, k0) + T4(qx1, k1)) + (T4(qx2, k2) + T4(qx3, k3));
    float sy = (T4(qy0, k0) + T4(qy1, k1)) + (T4(qy2, k2) + T4(qy3, k3));
    float sz = (T4(qz0, k0) + T4(qz1, k1)) + (T4(qz2, k2) + T4(qz3, k3));
    sw += __shfl_xor(sw, 1); sw += __shfl_xor(sw, 2);
    sx += __shfl_xor(sx, 1); sx += __shfl_xor(sx, 2);
    sy += __shfl_xor(sy, 1); sy += __shfl_xor(sy, 2);
    sz += __shfl_xor(sz, 1); sz += __shfl_xor(sz, 2);
    if (sub == 0) {
      int jj = j - jlo;
      sw += E2(cw0, cc.x) * wd0 + E2(cw1, cc.y) * wd1 + E2(cw2, cc.z) * wd2;
      sx += E2(cx0, cc.x) * wd0 + E2(cx1, cc.y) * wd1 + E2(cx2, cc.z) * wd2;
      sy += E2(cy0, cc.x) * wd0 + E2(cy1, cc.y) * wd1 + E2(cy2, cc.z) * wd2;
      sz += E2(cz0, cc.x) * wd0 + E2(cz1, cc.y) * wd1 + E2(cz2, cc.z) * wd2;
      float p0 = exp2_raw(sw * pscale);
      float p1 = exp2_raw(sx * pscale);
      float p2 = exp2_raw(sy * pscale);
      float p3 = exp2_raw(sz * pscale);
      s_score[0][jj] = p0; s_score[1][jj] = p1;
      s_score[2][jj] = p2; s_score[3][jj] = p3;
      lsw += p0; lsx += p1; lsy += p2; lsz += p3;
    }
  }

  // ---- sums: wave shfl reduce + cross-wave combine ----
#pragma unroll
  for (int off = 1; off < 64; off <<= 1) {
    lsw += __shfl_xor(lsw, off);
    lsx += __shfl_xor(lsx, off);
    lsy += __shfl_xor(lsy, off);
    lsz += __shfl_xor(lsz, off);
  }
  if (lane == 0) {
    s_red[0][wid] = lsw; s_red[1][wid] = lsx;
    s_red[2][wid] = lsy; s_red[3][wid] = lsz;
  }
  __syncthreads();
  float tw = s_red[0][0], tx = s_red[1][0], ty = s_red[2][0], tz = s_red[3][0];
#pragma unroll
  for (int w = 1; w < BT / 64; ++w) {
    tw += s_red[0][w]; tx += s_red[1][w];
    ty += s_red[2][w]; tz += s_red[3][w];
  }
  __syncthreads();   // done reading s_red before reuse; s_score visible

  // ---- phase 2: unnormalized o[c] = sum_j p_j * v[j,c], 4 j-groups ----
  const int c = tid & 63, g = tid >> 6;   // g in [0,4)
  float aw = 0.f, ax = 0.f, ay = 0.f, az = 0.f;
#pragma unroll 8
  for (int j2 = jlo + g; j2 < jhi; j2 += 4) {
    float v = kvp[(size_t)j2 * 128 + 64 + c];
    int jj = j2 - jlo;
    aw = fmaf(s_score[0][jj], v, aw);
    ax = fmaf(s_score[1][jj], v, ax);
    ay = fmaf(s_score[2][jj], v, ay);
    az = fmaf(s_score[3][jj], v, az);
  }
  s_red[0][tid] = aw; s_red[1][tid] = ax;
  s_red[2][tid] = ay; s_red[3][tid] = az;
  __syncthreads();

  float* P = part + (size_t)(qquad * NJQ + h) * PSTRIDE;
  if (g == 0) {
    float uw = 0.f, ux = 0.f, uy = 0.f, uz = 0.f;
#pragma unroll
    for (int gg = 0; gg < 4; ++gg) {
      uw += s_red[0][gg * 64 + c];
      ux += s_red[1][gg * 64 + c];
      uy += s_red[2][gg * 64 + c];
      uz += s_red[3][gg * 64 + c];
    }
    P[4 + 0 * 64 + c] = uw;
    P[4 + 1 * 64 + c] = ux;
    P[4 + 2 * 64 + c] = uy;
    P[4 + 3 * 64 + c] = uz;
    if (c == 0) { P[0] = tw; P[1] = tx; P[2] = ty; P[3] = tz; }
  }
}

// ---------------------------------------------------------------------------
// Kernel B2: merge eighths + projection. Block = 4 queries x 64 channels
// (one qquad per block).
// ---------------------------------------------------------------------------
__global__ __launch_bounds__(256) void attn_merge(
    const float* __restrict__ part, const float* __restrict__ Wproj,
    const float* __restrict__ bproj, float* __restrict__ out) {
  __shared__ float s_o[4][CH];
  const int tid = threadIdx.x;
  const int qs = tid >> 6, c = tid & 63;
  const int qquad = blockIdx.x;
  const int i = qquad * 4 + qs;

  float ssum = 0.f, osum = 0.f;
#pragma unroll
  for (int h = 0; h < NJQ; ++h) {
    const float* P = part + (size_t)(qquad * NJQ + h) * PSTRIDE;
    ssum += P[qs];
    osum += P[4 + qs * 64 + c];
  }
  s_o[qs][c] = osum / ssum;
  __syncthreads();

  float acc = 0.f;
#pragma unroll 16
  for (int r = 0; r < CH; ++r)
    acc = fmaf(s_o[qs][r], Wproj[r * CH + c], acc);
  out[(size_t)i * CH + c] = acc + bproj[c];
}

// ---------------------------------------------------------------------------
extern "C" void kernel_launch(void* const* d_in, const int* in_sizes, int n_in,
                              void* d_out, int out_size, void* d_ws, size_t ws_size,
                              hipStream_t stream) {
  const float* q      = (const float*)d_in[0];
  const float* qc     = (const float*)d_in[1];
  const float* kv     = (const float*)d_in[2];
  const float* kvc    = (const float*)d_in[3];
  const float* Wq     = (const float*)d_in[4];
  const float* Wkv    = (const float*)d_in[5];
  const float* Wdelta = (const float*)d_in[6];
  const float* Wproj  = (const float*)d_in[7];
  const float* bproj  = (const float*)d_in[8];
  float* outp = (float*)d_out;

  float* qp   = (float*)d_ws;                              // 512*64
  float* kvp  = qp + NQ * CH;                              // 2562*128
  float* part = kvp + (size_t)NKV * 2 * CH;                // 128*8*260
  float* kvc4 = part + (size_t)(NQ / QB) * NJQ * PSTRIDE;  // 2562*4

  gemm_qkv<<<NKVB + NQB + NCB, 256, 0, stream>>>(q, kv, Wq, Wkv, kvc, qp, kvp, kvc4);
  attn_part<<<(NQ / QB) * NJQ, BT, 0, stream>>>(qp, kvp, qc, kvc4, Wdelta, part);
  attn_merge<<<NQ / QB, 256, 0, stream>>>(part, Wproj, bproj, outp);
}